// Round 13
// baseline (145.610 us; speedup 1.0000x reference)
//
#include <hip/hip_runtime.h>
#include <hip/hip_bf16.h>
#include <hip/hip_fp16.h>
#include <stdint.h>

#define K_DIM 4096
#define N_DIM 11008
#define M_DIM 512
#define PK_ROW 5504          // int32 code-words per k-row (one per n-pair)
#define SC_ROW 172           // scale blocks per k-row

typedef __attribute__((ext_vector_type(4))) float f32x4;
typedef __attribute__((ext_vector_type(4))) int i32x4;
typedef __attribute__((ext_vector_type(4))) unsigned int u32x4;
typedef __attribute__((ext_vector_type(8))) _Float16 half8;
typedef __attribute__((ext_vector_type(8))) short bf16x8;

__constant__ float NF4[16] = {
    -1.0f, -0.6961928009986877f, -0.5250730514526367f, -0.39491748809814453f,
    -0.28444138169288635f, -0.18477343022823334f, -0.09105003625154495f, 0.0f,
    0.07958029955625534f, 0.16093020141124725f, 0.24611230194568634f,
    0.33791524171829224f, 0.44070982933044434f, 0.5626170039176941f,
    0.7229568362236023f, 1.0f};

union H8 { u32x4 v; half8 h; };

__device__ __forceinline__ unsigned h2mul(unsigned a, unsigned b) {
  union { __half2 h; unsigned u; } x, y, r;
  x.u = a; y.u = b;
  r.h = x.h * y.h;           // v_pk_mul_f16
  return r.u;
}
__device__ __forceinline__ unsigned hpack(float a, float b) {
  union { __half2 h; unsigned u; } c;
  c.h = __floats2half2_rn(a, b);
  return c.u;
}
__device__ __forceinline__ unsigned f2bf(float v) {  // for fallback kernel
  union { __hip_bfloat16 h; unsigned short u; } cv;
  cv.h = __float2bfloat16(v);
  return (unsigned)cv.u;
}

// ---- prep: B dequant to f16 fragment layout + A conv, one kernel ----
// bid [0,5504):   B tiles: kt=bid&63 (64 k), nt=bid>>6 (128 n). packed -> LDS
//                 transpose -> LUT dequant -> wsb unit (n16,k32)=1KB,
//                 idx = (n16*128+k32)*256 + lane*4; lane l holds
//                 B[k32*32+(l>>4)*8+j][n16*16+(l&15)], j=0..7 (same frag
//                 structure the fused STEP used — proven layout).
// bid [5504,6528): A conv (x fp32 -> f16 fragment layout in wsa)
__global__ __launch_bounds__(256) void prep_fused(
    const float* __restrict__ x, const int* __restrict__ packed,
    const float* __restrict__ scales, unsigned* __restrict__ wsa,
    unsigned* __restrict__ wsb) {
  const int bid = blockIdx.x;
  const int t = threadIdx.x;
  if (bid < 5504) {
    const int kt = bid & 63;
    const int nt = bid >> 6;
    __shared__ unsigned LutR[256 * 32];            // 32-copy LUT (0-conflict)
    __shared__ __align__(4) unsigned char Sb[128 * 36];  // [n_loc][kp_loc]
    __shared__ __align__(16) unsigned sL[64];      // [nbl(2)][kpl(32)] f16x2
    {
      const int c = t & 31;
      const int b0 = t >> 5;
#pragma unroll
      for (int i = 0; i < 32; ++i) {
        const int b = b0 + 8 * i;
        LutR[b * 32 + c] = hpack(NF4[(b >> 4) & 15], NF4[b & 15]);
      }
    }
    if (t < 64) {  // scale pairs: k = kt*64 + kpl*2 (+1), nb = nt*2 + nbl
      const int kpl = t >> 1;
      const int nbl = t & 1;
      const int nbg = nt * 2 + nbl;
      const float s0 = scales[(size_t)(kt * 64 + kpl * 2) * SC_ROW + nbg];
      const float s1 = scales[(size_t)(kt * 64 + kpl * 2 + 1) * SC_ROW + nbg];
      sL[nbl * 32 + kpl] = hpack(s0, s1);
    }
    {  // transpose stage (prep_codes stage-1, proven): byte(n,kp)
      const int npl = t & 63;
      const int kq = t >> 6;
      const int np = nt * 64 + npl;
#pragma unroll
      for (int i = 0; i < 8; ++i) {
        const int kpl = kq + i * 4;
        const int k = kt * 64 + kpl * 2;
        const int w0 = packed[(size_t)k * PK_ROW + np];
        const int w1 = packed[(size_t)(k + 1) * PK_ROW + np];
        Sb[(npl * 2) * 36 + kpl] =
            (unsigned char)((((w0 >> 4) & 15) << 4) | ((w1 >> 4) & 15));
        Sb[(npl * 2 + 1) * 36 + kpl] =
            (unsigned char)(((w0 & 15) << 4) | (w1 & 15));
      }
    }
    __syncthreads();
    // dequant stage: 16 units (bn 0..7, bk 0..1), wave w does uid w*4..w*4+3
    const int w = t >> 6;
    const int lane = t & 63;
    const int l15 = lane & 15;
    const int l4 = lane >> 4;
    const int lb = lane & 31;
#pragma unroll
    for (int u = 0; u < 4; ++u) {
      const int uid = w * 4 + u;
      const int bn = uid >> 1;
      const int bk = uid & 1;
      const int n_local = bn * 16 + l15;
      const int kp_base = bk * 16 + l4 * 4;
      const unsigned sw = *(const unsigned*)(&Sb[n_local * 36 + kp_base]);
      const u32x4 sx = *(const u32x4*)(&sL[(bn >> 2) * 32 + kp_base]);
      u32x4 d;
      d[0] = h2mul(LutR[((sw & 255u) << 5) | lb], sx[0]);
      d[1] = h2mul(LutR[(((sw >> 8) & 255u) << 5) | lb], sx[1]);
      d[2] = h2mul(LutR[(((sw >> 16) & 255u) << 5) | lb], sx[2]);
      d[3] = h2mul(LutR[((sw >> 24) << 5) | lb], sx[3]);
      const size_t unit = (size_t)(nt * 8 + bn) * 128 + kt * 2 + bk;
      *(u32x4*)(wsb + unit * 256 + lane * 4) = d;
    }
  } else {
    // A conv: unit (m16,k32)=1KB; lane l holds A[m16*16+(l&15)][k32*32+(l>>4)*8..+8)
    const int wid = (bid - 5504) * 4 + (t >> 6);
    const int lane = t & 63;
    const int m16 = wid >> 7, k32 = wid & 127;
    const int m = m16 * 16 + (lane & 15);
    const int k = k32 * 32 + (lane >> 4) * 8;
    const float* src = x + (size_t)m * K_DIM + k;
    f32x4 v0 = *(const f32x4*)src;
    f32x4 v1 = *(const f32x4*)(src + 4);
    u32x4 d;
    d[0] = hpack(v0[0], v0[1]);
    d[1] = hpack(v0[2], v0[3]);
    d[2] = hpack(v1[0], v1[1]);
    d[3] = hpack(v1[2], v1[3]);
    *(u32x4*)(wsa + (size_t)wid * 256 + lane * 4) = d;
  }
}

// ---- main GEMM: pure load+MFMA (dequant hoisted to prep) ----
// R13: R9-R12 all pinned at ~67us because gather(26us)+VALU(24us)+MFMA(19us)
// serialized on the per-wave chain. With B pre-dequanted: per k-step = 8
// VMEM dwordx4 + 16 MFMA, nothing else. 512t blocks, tile 256x128, 8 waves
// of 64x64, KS k-split, grid 86*2*KS. XCD gets fixed (kh,m_idx): A quarter
// 512KB L2-resident, B slice 22.5MB read once per XCD.
template <int KS>
__global__ __launch_bounds__(512) void nf4_gemmB(
    const unsigned* __restrict__ wsa, const unsigned* __restrict__ wsb,
    const float* __restrict__ bias, float* __restrict__ cout) {
  const int bid = blockIdx.x;
  const int C = 2 * KS;                // (m_idx, kh) combos
  const int xg = bid % C;
  const int n_idx = bid / C;           // 0..85
  const int kh = xg % KS;
  const int m_idx = xg / KS;           // 0..1
  const int m_tile = m_idx * 256;
  const int n_tile = n_idx * 128;

  const int t = threadIdx.x;
  const int lane = t & 63;
  const int wid = t >> 6;              // 0..7
  const int wm4 = wid >> 1;            // wave m-quarter (64 of 256)
  const int wnh = wid & 1;             // wave n-half (64 of 128)
  const int l15 = lane & 15;
  const int kslice = lane >> 4;
  const int m16w = (m_tile >> 4) + wm4 * 4;
  const int nf0 = (n_tile >> 4) + wnh * 4;

  unsigned ab[4], bb[4];
#pragma unroll
  for (int i = 0; i < 4; ++i) {
    ab[i] = (unsigned)(m16w + i) * 32768 + lane * 4;
    bb[i] = (unsigned)(nf0 + i) * 32768 + lane * 4;
  }

  f32x4 acc[4][4];
#pragma unroll
  for (int i = 0; i < 4; ++i)
#pragma unroll
    for (int j = 0; j < 4; ++j) acc[i][j] = (f32x4){0.f, 0.f, 0.f, 0.f};

  const int NS = 128 / KS;             // k32-steps per block
  const int s_base = kh * NS;

  auto LOAD = [&](int sl, u32x4* A, u32x4* B) {
    const unsigned s = (unsigned)(s_base + sl);
#pragma unroll
    for (int i = 0; i < 4; ++i) A[i] = *(const u32x4*)(wsa + ab[i] + 256u * s);
#pragma unroll
    for (int j = 0; j < 4; ++j) B[j] = *(const u32x4*)(wsb + bb[j] + 256u * s);
  };
  auto STEP = [&](const u32x4* A, const u32x4* B) {
    H8 a[4], b[4];
#pragma unroll
    for (int i = 0; i < 4; ++i) a[i].v = A[i];
#pragma unroll
    for (int j = 0; j < 4; ++j) b[j].v = B[j];
#pragma unroll
    for (int j = 0; j < 4; ++j)
#pragma unroll
      for (int i = 0; i < 4; ++i)
        acc[i][j] = __builtin_amdgcn_mfma_f32_16x16x32_f16(a[i].h, b[j].h, acc[i][j], 0, 0, 0);
  };

  u32x4 XA[4], XB[4], YA[4], YB[4];
  LOAD(0, XA, XB);
#pragma unroll 1
  for (int s = 0; s < NS; s += 2) {
    LOAD(s + 1, YA, YB);               // s+1 <= NS-1 always
    STEP(XA, XB);
    if (s + 2 < NS) LOAD(s + 2, XA, XB);
    STEP(YA, YB);
  }

  // epilogue: partial store (bias folded in for KS==1); col=l15, row=kslice*4+r
  float* dst = cout + (size_t)kh * ((size_t)M_DIM * N_DIM);
#pragma unroll
  for (int j = 0; j < 4; ++j) {
    const int gc = n_tile + wnh * 64 + j * 16 + l15;
    const float bi = (KS == 1) ? bias[gc] : 0.f;
#pragma unroll
    for (int fm = 0; fm < 4; ++fm) {
#pragma unroll
      for (int r = 0; r < 4; ++r) {
        const int gr = m_tile + wm4 * 64 + fm * 16 + kslice * 4 + r;
        dst[(size_t)gr * N_DIM + gc] = acc[fm][j][r] + bi;
      }
    }
  }
}

// ---- reduce: out = p0+..+p(KS-1) + bias ----
template <int KS>
__global__ __launch_bounds__(256) void reduce_bias(
    const float* __restrict__ parts, const float* __restrict__ bias,
    float* __restrict__ out) {
  const int tot4 = (M_DIM * N_DIM) / 4;
  const int stride = gridDim.x * 256;
  const size_t MN = (size_t)M_DIM * N_DIM;
  for (int i = blockIdx.x * 256 + threadIdx.x; i < tot4; i += stride) {
    const int e0 = i * 4;
    const int col = e0 % N_DIM;
    f32x4 s = *(const f32x4*)(parts + e0);
#pragma unroll
    for (int p = 1; p < KS; ++p) s += *(const f32x4*)(parts + p * MN + e0);
    s += *(const f32x4*)(bias + col);
    *(f32x4*)(out + e0) = s;
  }
}

// ---- fallback (round-1 kernel, proven 155us): used only if ws tiny ----
#define FLDS 72
__global__ __launch_bounds__(256) void nf4_gemm_fused(
    const float* __restrict__ x, const int* __restrict__ packed,
    const float* __restrict__ scales, const float* __restrict__ bias,
    float* __restrict__ out) {
  __shared__ unsigned short AldsF[128 * FLDS];
  __shared__ unsigned short BldsF[128 * FLDS];
  __shared__ float2 Lut[256];
  const int t = threadIdx.x;
  const int bid = blockIdx.x;
  const int swz = (bid & 7) * 43 + (bid >> 3);
  const int m_tile = (swz / 86) * 128;
  const int n_tile = (swz % 86) * 128;
  Lut[t] = make_float2(NF4[(t >> 4) & 15], NF4[t & 15]);
  const int lane = t & 63;
  const int wid = t >> 6;
  const int wm = (wid >> 1) * 64;
  const int wn = (wid & 1) * 64;
  const int l15 = lane & 15;
  const int l4 = lane >> 4;
  f32x4 acc[4][4];
#pragma unroll
  for (int i = 0; i < 4; ++i)
#pragma unroll
    for (int j = 0; j < 4; ++j) acc[i][j] = (f32x4){0.f, 0.f, 0.f, 0.f};
  const int mlane = t & 15;
  const int n_sub = mlane * 8;
  const int k_sub = 4 * (((t >> 4) + mlane) & 15);
  const int c4 = t & 15;
  const int r0 = t >> 4;
  for (int k0 = 0; k0 < K_DIM; k0 += 64) {
    __syncthreads();
#pragma unroll
    for (int i = 0; i < 8; ++i) {
      const int row = r0 + 16 * i;
      f32x4 xv = *(const f32x4*)(x + (size_t)(m_tile + row) * K_DIM + k0 + c4 * 4);
      uint2 d;
      d.x = f2bf(xv[0]) | (f2bf(xv[1]) << 16);
      d.y = f2bf(xv[2]) | (f2bf(xv[3]) << 16);
      *(uint2*)(&AldsF[row * FLDS + c4 * 4]) = d;
    }
    {
      const int* pk = packed + (size_t)(k0 + k_sub) * PK_ROW + ((n_tile + n_sub) >> 1);
      i32x4 w[4];
      float s[4];
#pragma unroll
      for (int kk = 0; kk < 4; ++kk) {
        w[kk] = *(const i32x4*)(pk + (size_t)kk * PK_ROW);
        s[kk] = scales[(size_t)(k0 + k_sub + kk) * SC_ROW + ((n_tile + n_sub) >> 6)];
      }
      float v[4][8];
#pragma unroll
      for (int kk = 0; kk < 4; ++kk)
#pragma unroll
        for (int e = 0; e < 4; ++e) {
          const int b = w[kk][e] & 0xFF;
          const float2 p = Lut[b];
          v[kk][2 * e] = p.x * s[kk];
          v[kk][2 * e + 1] = p.y * s[kk];
        }
#pragma unroll
      for (int j = 0; j < 8; ++j) {
        uint2 d;
        d.x = f2bf(v[0][j]) | (f2bf(v[1][j]) << 16);
        d.y = f2bf(v[2][j]) | (f2bf(v[3][j]) << 16);
        *(uint2*)(&BldsF[(n_sub + j) * FLDS + k_sub]) = d;
      }
    }
    __syncthreads();
#pragma unroll
    for (int ks = 0; ks < 2; ++ks) {
      bf16x8 af[4], bfv[4];
#pragma unroll
      for (int fm = 0; fm < 4; ++fm)
        af[fm] = *(const bf16x8*)(&AldsF[(wm + fm * 16 + l15) * FLDS + ks * 32 + l4 * 8]);
#pragma unroll
      for (int fn = 0; fn < 4; ++fn)
        bfv[fn] = *(const bf16x8*)(&BldsF[(wn + fn * 16 + l15) * FLDS + ks * 32 + l4 * 8]);
#pragma unroll
      for (int fm = 0; fm < 4; ++fm)
#pragma unroll
        for (int fn = 0; fn < 4; ++fn)
          acc[fm][fn] = __builtin_amdgcn_mfma_f32_16x16x32_bf16(af[fm], bfv[fn], acc[fm][fn], 0, 0, 0);
    }
  }
#pragma unroll
  for (int fn = 0; fn < 4; ++fn) {
    const float bi = bias[n_tile + wn + fn * 16 + l15];
#pragma unroll
    for (int fm = 0; fm < 4; ++fm)
#pragma unroll
      for (int r = 0; r < 4; ++r) {
        const int gr = m_tile + wm + fm * 16 + l4 * 4 + r;
        out[(size_t)gr * N_DIM + n_tile + wn + fn * 16 + l15] = acc[fm][fn][r] + bi;
      }
  }
}

extern "C" void kernel_launch(void* const* d_in, const int* in_sizes, int n_in,
                              void* d_out, int out_size, void* d_ws, size_t ws_size,
                              hipStream_t stream) {
  const float* x = (const float*)d_in[0];
  const int* packed = (const int*)d_in[1];
  const float* scales = (const float*)d_in[2];
  const float* bias = (const float*)d_in[3];
  float* out = (float*)d_out;

  const size_t A_BYTES = (size_t)M_DIM * K_DIM * 2;            //  4,194,304
  const size_t B_BYTES = (size_t)N_DIM * K_DIM * 2;            // 90,177,536
  const size_t MN_BYTES = (size_t)M_DIM * N_DIM * 4;           // 22,544,384
  const size_t base = A_BYTES + B_BYTES;                       // 94.4 MB
  const size_t need1 = base;                                   // KS1: direct out
  const size_t need2 = base + 2 * MN_BYTES;                    // 139.5 MB
  const size_t need4 = base + 4 * MN_BYTES;                    // 184.5 MB

  if (ws_size >= need1) {
    unsigned* wsa = (unsigned*)d_ws;
    unsigned* wsb = (unsigned*)((char*)d_ws + A_BYTES);
    float* cpart = (float*)((char*)d_ws + base);
    prep_fused<<<dim3(6528), dim3(256), 0, stream>>>(x, packed, scales, wsa, wsb);
    if (ws_size >= need4) {
      nf4_gemmB<4><<<dim3(688), dim3(512), 0, stream>>>(wsa, wsb, bias, cpart);
      reduce_bias<4><<<dim3(2048), dim3(256), 0, stream>>>(cpart, bias, out);
    } else if (ws_size >= need2) {
      nf4_gemmB<2><<<dim3(344), dim3(512), 0, stream>>>(wsa, wsb, bias, cpart);
      reduce_bias<2><<<dim3(2048), dim3(256), 0, stream>>>(cpart, bias, out);
    } else {
      nf4_gemmB<1><<<dim3(172), dim3(512), 0, stream>>>(wsa, wsb, bias, out);
    }
  } else {
    nf4_gemm_fused<<<dim3(344), dim3(256), 0, stream>>>(x, packed, scales, bias, out);
  }
}